// Round 15
// baseline (151.328 us; speedup 1.0000x reference)
//
#include <hip/hip_runtime.h>

#define FF_N 4096
#define S64  0.015625f   // 1/64 per FWHT (total 1/4096)

typedef float  v2f __attribute__((ext_vector_type(2)));
typedef __fp16 pkhalf2 __attribute__((ext_vector_type(2)));

// Packed fp32 (VOP3P) — both rows' butterfly op in one instruction.
__device__ __forceinline__ v2f pk_add(v2f a, v2f b) {
    v2f d; asm("v_pk_add_f32 %0, %1, %2" : "=v"(d) : "v"(a), "v"(b)); return d;
}
__device__ __forceinline__ v2f pk_sub(v2f a, v2f b) {
    v2f d; asm("v_pk_add_f32 %0, %1, %2 neg_lo:[0,1] neg_hi:[0,1]"
               : "=v"(d) : "v"(a), "v"(b)); return d;
}
__device__ __forceinline__ void h16p(v2f v[16]) {
#pragma unroll
    for (int b = 1; b < 16; b <<= 1) {
#pragma unroll
        for (int r = 0; r < 16; ++r) {
            if ((r & b) == 0) {
                const v2f u = v[r], w = v[r | b];
                v[r]     = pk_add(u, w);
                v[r | b] = pk_sub(u, w);
            }
        }
    }
}

// f16x2 pack/unpack: one LDS dword holds both rows' same element.
__device__ __forceinline__ unsigned pkpack(v2f a) {
    union { pkhalf2 h; unsigned u; } cv;
    cv.h = __builtin_amdgcn_cvt_pkrtz(a[0], a[1]);
    return cv.u;
}
__device__ __forceinline__ v2f pkunpack(unsigned u) {
    union { unsigned u; pkhalf2 h; } cv; cv.u = u;
    return (v2f){(float)cv.h[0], (float)cv.h[1]};
}

// Layouts identical to R14 (bijective, conflict-free, validated):
//  A: aA = (d2<<8)|((d1>>3)<<7)|((d0>>2)<<5)|(((d1&7)^(d0>>2))<<2)|(d0&3)
//  P: aP = (d2<<8)|((d0>>3)<<7)|((d1>>2)<<5)|(((d0&7)^(d1>>2))<<2)|(d1&3)
//  W: aW = (d1<<8)|((d0>>3)<<7)|((d2>>2)<<5)|(((d0&7)^(d2>>2))<<2)|(d2&3)
// Shared write base WB[q] = (T<<8)|((c>>3)<<7)|(q<<5)|(((c&7)^q)<<2).

__global__ void ff_setup(const float* __restrict__ diag_s,
                         const float* __restrict__ diag_g,
                         const int*   __restrict__ perm,
                         int*   __restrict__ gaddr,
                         float* __restrict__ gg,
                         float* __restrict__ ss) {
    const int k   = blockIdx.x * 256 + threadIdx.x;
    const int pe  = perm[k];
    const int d2p = pe >> 8, d1p = (pe >> 4) & 15, d0p = pe & 15;
    gaddr[k] = (d1p << 8) | ((d0p >> 3) << 7) | ((d2p >> 2) << 5)
             | (((d0p & 7) ^ (d2p >> 2)) << 2) | (d2p & 3);
    gg[k] = diag_g[k] * S64;
    ss[k] = diag_s[k] * S64;
}

__device__ __forceinline__ void jwrite(const v2f v[16], unsigned* __restrict__ L,
                                       const int WB[4]) {
#pragma unroll
    for (int q = 0; q < 4; ++q) {
        uint4 w;
        w.x = pkpack(v[4 * q + 0]); w.y = pkpack(v[4 * q + 1]);
        w.z = pkpack(v[4 * q + 2]); w.w = pkpack(v[4 * q + 3]);
        *(uint4*)&L[WB[q]] = w;
    }
}

// Phases P1(tail)..P6 for one row-pair whose v[] is already multiplied by
// diag_b. R14-verbatim access patterns.
__device__ __forceinline__ void ff_tail(
    v2f v[16], unsigned* __restrict__ L, const int WB[4],
    const int AR0, const int PR0,
    const int*   __restrict__ gaddr,
    const float* __restrict__ gg,
    const float* __restrict__ ss,
    const int t, const int c,
    float* __restrict__ outA, float* __restrict__ outB)
{
    // ---- P1 tail: h16(d0); A-write ----
    h16p(v);
    jwrite(v, L, WB);
    __syncthreads();

    // ---- P2: A-read all d1; h16(d1); P-write ----
#pragma unroll
    for (int j = 0; j < 16; ++j)
        v[j] = pkunpack(L[AR0 | ((j >> 3) << 7) | (((j & 7) ^ (c >> 2)) << 2)]);
    h16p(v);
    __syncthreads();
    jwrite(v, L, WB);
    __syncthreads();

    // ---- P3: P-read all d2; h16(d2) -> FWHT1 done; W-write ----
#pragma unroll
    for (int j = 0; j < 16; ++j) v[j] = pkunpack(L[PR0 | (j << 8)]);
    h16p(v);
    __syncthreads();
    jwrite(v, L, WB);
    __syncthreads();

    // ---- P4: precomputed gather * gg; h16(d0'); A-write ----
    {
        const int4*   __restrict__ ga4 = (const int4*)(gaddr + 16 * t);
        const float4* __restrict__ gg4 = (const float4*)(gg + 16 * t);
#pragma unroll
        for (int q = 0; q < 4; ++q) {
            const int4   pa = ga4[q];
            const float4 gv = gg4[q];
            const v2f a0 = pkunpack(L[pa.x]), a1 = pkunpack(L[pa.y]);
            const v2f a2 = pkunpack(L[pa.z]), a3 = pkunpack(L[pa.w]);
            v[4 * q + 0] = (v2f){a0[0] * gv.x, a0[1] * gv.x};
            v[4 * q + 1] = (v2f){a1[0] * gv.y, a1[1] * gv.y};
            v[4 * q + 2] = (v2f){a2[0] * gv.z, a2[1] * gv.z};
            v[4 * q + 3] = (v2f){a3[0] * gv.w, a3[1] * gv.w};
        }
        h16p(v);
    }
    __syncthreads();
    jwrite(v, L, WB);
    __syncthreads();

    // ---- P5: A-read; h16(d1'); P-write ----
#pragma unroll
    for (int j = 0; j < 16; ++j)
        v[j] = pkunpack(L[AR0 | ((j >> 3) << 7) | (((j & 7) ^ (c >> 2)) << 2)]);
    h16p(v);
    __syncthreads();
    jwrite(v, L, WB);
    __syncthreads();

    // ---- P6: P-read; h16(d2'); dense NT store out[256j + t] * ss ----
#pragma unroll
    for (int j = 0; j < 16; ++j) v[j] = pkunpack(L[PR0 | (j << 8)]);
    h16p(v);
#pragma unroll
    for (int j = 0; j < 16; ++j) {
        const int e = 256 * j + t;
        const float s = ss[e];
        __builtin_nontemporal_store(v[j][0] * s, &outA[e]);
        __builtin_nontemporal_store(v[j][1] * s, &outB[e]);
    }
}

// TWO sequential row-pairs per block; pair-2's global loads are issued right
// after pair-1's multiply, so they stay in flight beneath pair-1's entire
// LDS pipeline (~90% of block lifetime) -> HBM burst gaps get filled.
__global__ __launch_bounds__(256, 6) void fastfood_pp_kernel(
    const float* __restrict__ x,
    const float* __restrict__ diag_b,
    const int*   __restrict__ gaddr,
    const float* __restrict__ gg,
    const float* __restrict__ ss,
    float* __restrict__ out)
{
    __shared__ __align__(16) unsigned L[FF_N];   // 16 KB (f16x2-packed pairs)
    const int t = threadIdx.x;
    const int T = t >> 4, c = t & 15;
    const size_t row0 = (size_t)blockIdx.x * 4;
    const float* __restrict__ xA = x + row0 * FF_N;
    const float* __restrict__ xB = xA + FF_N;
    const float* __restrict__ xC = xB + FF_N;
    const float* __restrict__ xD = xC + FF_N;
    float* __restrict__ oA = out + row0 * FF_N;
    float* __restrict__ oB = oA + FF_N;
    float* __restrict__ oC = oB + FF_N;
    float* __restrict__ oD = oC + FF_N;

    int WB[4];
#pragma unroll
    for (int q = 0; q < 4; ++q)
        WB[q] = (T << 8) | ((c >> 3) << 7) | (q << 5) | (((c & 7) ^ q) << 2);
    const int AR0 = (T << 8) | ((c >> 2) << 5) | (c & 3);
    const int PR0 = ((c >> 3) << 7) | ((T >> 2) << 5)
                  | (((c & 7) ^ (T >> 2)) << 2) | (T & 3);

    v2f v[16];

    // ---- pair-1 loads + multiply ----
    {
        const float4* __restrict__ xa4 = (const float4*)(xA + 16 * t);
        const float4* __restrict__ xb4 = (const float4*)(xB + 16 * t);
        const float4* __restrict__ b4  = (const float4*)(diag_b + 16 * t);
#pragma unroll
        for (int q = 0; q < 4; ++q) {
            const float4 bv = b4[q];
            const float4 av = xa4[q];
            const float4 wv = xb4[q];
            v[4 * q + 0] = (v2f){av.x * bv.x, wv.x * bv.x};
            v[4 * q + 1] = (v2f){av.y * bv.y, wv.y * bv.y};
            v[4 * q + 2] = (v2f){av.z * bv.z, wv.z * bv.z};
            v[4 * q + 3] = (v2f){av.w * bv.w, wv.w * bv.w};
        }
    }

    // ---- issue pair-2 prefetch NOW (stays in flight under pair-1's pipeline) ----
    float4 rc[4], rd[4];
    {
        const float4* __restrict__ xc4 = (const float4*)(xC + 16 * t);
        const float4* __restrict__ xd4 = (const float4*)(xD + 16 * t);
#pragma unroll
        for (int q = 0; q < 4; ++q) { rc[q] = xc4[q]; rd[q] = xd4[q]; }
    }

    // ---- pair-1 pipeline ----
    ff_tail(v, L, WB, AR0, PR0, gaddr, gg, ss, t, c, oA, oB);

    __syncthreads();   // pair-1 P6 LDS reads done before pair-2 overwrites

    // ---- pair-2 multiply (diag_b reloaded: L2-resident, shared) ----
    {
        const float4* __restrict__ b4 = (const float4*)(diag_b + 16 * t);
#pragma unroll
        for (int q = 0; q < 4; ++q) {
            const float4 bv = b4[q];
            v[4 * q + 0] = (v2f){rc[q].x * bv.x, rd[q].x * bv.x};
            v[4 * q + 1] = (v2f){rc[q].y * bv.y, rd[q].y * bv.y};
            v[4 * q + 2] = (v2f){rc[q].z * bv.z, rd[q].z * bv.z};
            v[4 * q + 3] = (v2f){rc[q].w * bv.w, rd[q].w * bv.w};
        }
    }

    // ---- pair-2 pipeline ----
    ff_tail(v, L, WB, AR0, PR0, gaddr, gg, ss, t, c, oC, oD);
}

extern "C" void kernel_launch(void* const* d_in, const int* in_sizes, int n_in,
                              void* d_out, int out_size, void* d_ws, size_t ws_size,
                              hipStream_t stream) {
    const float* x      = (const float*)d_in[0];
    const float* diag_s = (const float*)d_in[1];
    const float* diag_g = (const float*)d_in[2];
    const float* diag_b = (const float*)d_in[3];
    const int*   perm   = (const int*)d_in[4];
    float* out = (float*)d_out;

    int*   gaddr = (int*)d_ws;
    float* gg    = (float*)d_ws + FF_N;
    float* ss    = (float*)d_ws + 2 * FF_N;

    ff_setup<<<FF_N / 256, 256, 0, stream>>>(diag_s, diag_g, perm, gaddr, gg, ss);

    const int batch = in_sizes[0] / FF_N;   // 16384 rows
    fastfood_pp_kernel<<<batch / 4, 256, 0, stream>>>(x, diag_b, gaddr, gg, ss, out);
}

// Round 16
// 90.075 us; speedup vs baseline: 1.6800x; 1.6800x over previous
//
#include <hip/hip_runtime.h>

#define FF_N 4096
#define S64  0.015625f   // 1/64 per FWHT (total 1/4096)

typedef float  v2f __attribute__((ext_vector_type(2)));
typedef __fp16 pkhalf2 __attribute__((ext_vector_type(2)));

// Packed fp32 (VOP3P) — both rows' butterfly op in one instruction.
__device__ __forceinline__ v2f pk_add(v2f a, v2f b) {
    v2f d; asm("v_pk_add_f32 %0, %1, %2" : "=v"(d) : "v"(a), "v"(b)); return d;
}
__device__ __forceinline__ v2f pk_sub(v2f a, v2f b) {
    v2f d; asm("v_pk_add_f32 %0, %1, %2 neg_lo:[0,1] neg_hi:[0,1]"
               : "=v"(d) : "v"(a), "v"(b)); return d;
}
__device__ __forceinline__ void h16p(v2f v[16]) {
#pragma unroll
    for (int b = 1; b < 16; b <<= 1) {
#pragma unroll
        for (int r = 0; r < 16; ++r) {
            if ((r & b) == 0) {
                const v2f u = v[r], w = v[r | b];
                v[r]     = pk_add(u, w);
                v[r | b] = pk_sub(u, w);
            }
        }
    }
}

// f16x2 pack/unpack: one LDS dword holds both rows' same element.
__device__ __forceinline__ unsigned pkpack(v2f a) {
    union { pkhalf2 h; unsigned u; } cv;
    cv.h = __builtin_amdgcn_cvt_pkrtz(a[0], a[1]);
    return cv.u;
}
__device__ __forceinline__ v2f pkunpack(unsigned u) {
    union { unsigned u; pkhalf2 h; } cv; cv.u = u;
    return (v2f){(float)cv.h[0], (float)cv.h[1]};
}

// Layouts identical to R14 (bijective, conflict-free, validated on HW):
//  A: aA = (d2<<8)|((d1>>3)<<7)|((d0>>2)<<5)|(((d1&7)^(d0>>2))<<2)|(d0&3)
//  P: aP = (d2<<8)|((d0>>3)<<7)|((d1>>2)<<5)|(((d0&7)^(d1>>2))<<2)|(d1&3)
//  W: aW = (d1<<8)|((d0>>3)<<7)|((d2>>2)<<5)|(((d0&7)^(d2>>2))<<2)|(d2&3)
// Shared write base WB[q] = (T<<8)|((c>>3)<<7)|(q<<5)|(((c&7)^q)<<2).
// NEW in R16: ping-pong LDS buffers L0/L1 remove the 4 WAR barriers
// (P1w->L0; P2: r L0, w L1; P3: r L1, w L0; P4: gather L0, w L1;
//  P5: r L1, w L0; P6: r L0). 5 barriers total (RAW only).

__global__ void ff_setup(const float* __restrict__ diag_s,
                         const float* __restrict__ diag_g,
                         const int*   __restrict__ perm,
                         int*   __restrict__ gaddr,
                         float* __restrict__ gg,
                         float* __restrict__ ss) {
    const int k   = blockIdx.x * 256 + threadIdx.x;
    const int pe  = perm[k];
    const int d2p = pe >> 8, d1p = (pe >> 4) & 15, d0p = pe & 15;
    gaddr[k] = (d1p << 8) | ((d0p >> 3) << 7) | ((d2p >> 2) << 5)
             | (((d0p & 7) ^ (d2p >> 2)) << 2) | (d2p & 3);
    gg[k] = diag_g[k] * S64;
    ss[k] = diag_s[k] * S64;
}

__global__ __launch_bounds__(256) void fastfood_db_kernel(
    const float* __restrict__ x,
    const float* __restrict__ diag_b,
    const int*   __restrict__ gaddr,
    const float* __restrict__ gg,
    const float* __restrict__ ss,
    float* __restrict__ out)
{
    __shared__ __align__(16) unsigned L0[FF_N];   // 16 KB (f16x2-packed pairs)
    __shared__ __align__(16) unsigned L1[FF_N];   // 16 KB (ping-pong partner)
    const int t = threadIdx.x;
    const int T = t >> 4, c = t & 15;
    const size_t rowA = (size_t)blockIdx.x * 2;
    const float* __restrict__ xA   = x   + rowA * FF_N;
    const float* __restrict__ xB   = xA  + FF_N;
    float* __restrict__       outA = out + rowA * FF_N;
    float* __restrict__       outB = outA + FF_N;

    // shared write bases (A-, P-, W-writes all use the same formula)
    int WB[4];
#pragma unroll
    for (int q = 0; q < 4; ++q)
        WB[q] = (T << 8) | ((c >> 3) << 7) | (q << 5) | (((c & 7) ^ q) << 2);
    const int AR0 = (T << 8) | ((c >> 2) << 5) | (c & 3);           // A-read base
    const int PR0 = ((c >> 3) << 7) | ((T >> 2) << 5)
                  | (((c & 7) ^ (T >> 2)) << 2) | (T & 3);          // P-read base

    v2f v[16];

#define JWRITE(Lbuf)                                                           \
    {                                                                          \
        _Pragma("unroll")                                                      \
        for (int q = 0; q < 4; ++q) {                                          \
            uint4 w;                                                           \
            w.x = pkpack(v[4 * q + 0]); w.y = pkpack(v[4 * q + 1]);            \
            w.z = pkpack(v[4 * q + 2]); w.w = pkpack(v[4 * q + 3]);            \
            *(uint4*)&(Lbuf)[WB[q]] = w;                                       \
        }                                                                      \
    }

    // ===== P1: load both rows * diag_b (float4, coalesced); h16(d0); A-write L0 =====
    {
        const float4* __restrict__ xa4 = (const float4*)(xA + 16 * t);
        const float4* __restrict__ xb4 = (const float4*)(xB + 16 * t);
        const float4* __restrict__ b4  = (const float4*)(diag_b + 16 * t);
#pragma unroll
        for (int q = 0; q < 4; ++q) {
            const float4 bv = b4[q];
            const float4 av = xa4[q];
            const float4 wv = xb4[q];
            v[4 * q + 0] = (v2f){av.x * bv.x, wv.x * bv.x};
            v[4 * q + 1] = (v2f){av.y * bv.y, wv.y * bv.y};
            v[4 * q + 2] = (v2f){av.z * bv.z, wv.z * bv.z};
            v[4 * q + 3] = (v2f){av.w * bv.w, wv.w * bv.w};
        }
        h16p(v);
        JWRITE(L0);
    }
    __syncthreads();   // B1: L0 ready

    // ===== P2: A-read L0 (all d1); h16(d1); P-write L1 =====
#pragma unroll
    for (int j = 0; j < 16; ++j)
        v[j] = pkunpack(L0[AR0 | ((j >> 3) << 7) | (((j & 7) ^ (c >> 2)) << 2)]);
    h16p(v);
    JWRITE(L1);
    __syncthreads();   // B2: L1 ready (and all L0 reads done)

    // ===== P3: P-read L1 (all d2); h16(d2) -> FWHT1 done; W-write L0 =====
#pragma unroll
    for (int j = 0; j < 16; ++j) v[j] = pkunpack(L1[PR0 | (j << 8)]);
    h16p(v);
    JWRITE(L0);
    __syncthreads();   // B3: L0 (gather source) ready

    // ===== P4: precomputed gather L0 * gg; h16(d0'); A-write L1 =====
    {
        const int4*   __restrict__ ga4 = (const int4*)(gaddr + 16 * t);
        const float4* __restrict__ gg4 = (const float4*)(gg + 16 * t);
#pragma unroll
        for (int q = 0; q < 4; ++q) {
            const int4   pa = ga4[q];
            const float4 gv = gg4[q];
            const v2f a0 = pkunpack(L0[pa.x]), a1 = pkunpack(L0[pa.y]);
            const v2f a2 = pkunpack(L0[pa.z]), a3 = pkunpack(L0[pa.w]);
            v[4 * q + 0] = (v2f){a0[0] * gv.x, a0[1] * gv.x};
            v[4 * q + 1] = (v2f){a1[0] * gv.y, a1[1] * gv.y};
            v[4 * q + 2] = (v2f){a2[0] * gv.z, a2[1] * gv.z};
            v[4 * q + 3] = (v2f){a3[0] * gv.w, a3[1] * gv.w};
        }
        h16p(v);
    }
    JWRITE(L1);
    __syncthreads();   // B4: L1 ready (and all L0 gather reads done)

    // ===== P5: A-read L1; h16(d1'); P-write L0 =====
#pragma unroll
    for (int j = 0; j < 16; ++j)
        v[j] = pkunpack(L1[AR0 | ((j >> 3) << 7) | (((j & 7) ^ (c >> 2)) << 2)]);
    h16p(v);
    JWRITE(L0);
    __syncthreads();   // B5: L0 ready

    // ===== P6: P-read L0; h16(d2'); DENSE NT store out[256j + t] * ss =====
#pragma unroll
    for (int j = 0; j < 16; ++j) v[j] = pkunpack(L0[PR0 | (j << 8)]);
    h16p(v);
#pragma unroll
    for (int j = 0; j < 16; ++j) {
        const int e = 256 * j + t;
        const float s = ss[e];
        __builtin_nontemporal_store(v[j][0] * s, &outA[e]);
        __builtin_nontemporal_store(v[j][1] * s, &outB[e]);
    }
#undef JWRITE
}

extern "C" void kernel_launch(void* const* d_in, const int* in_sizes, int n_in,
                              void* d_out, int out_size, void* d_ws, size_t ws_size,
                              hipStream_t stream) {
    const float* x      = (const float*)d_in[0];
    const float* diag_s = (const float*)d_in[1];
    const float* diag_g = (const float*)d_in[2];
    const float* diag_b = (const float*)d_in[3];
    const int*   perm   = (const int*)d_in[4];
    float* out = (float*)d_out;

    int*   gaddr = (int*)d_ws;
    float* gg    = (float*)d_ws + FF_N;
    float* ss    = (float*)d_ws + 2 * FF_N;

    ff_setup<<<FF_N / 256, 256, 0, stream>>>(diag_s, diag_g, perm, gaddr, gg, ss);

    const int batch = in_sizes[0] / FF_N;   // 16384 rows
    fastfood_db_kernel<<<batch / 2, 256, 0, stream>>>(x, diag_b, gaddr, gg, ss, out);
}